// Round 11
// baseline (204.216 us; speedup 1.0000x reference)
//
#include <hip/hip_runtime.h>
#include <hip/hip_bf16.h>

typedef __attribute__((ext_vector_type(8))) short bf16x8;
typedef __attribute__((ext_vector_type(4))) float f32x4;

#define HW_ 25600
#define HP_ 162
#define WP_ 162

__device__ __forceinline__ unsigned short f2bf(float f) {
    union { float f; unsigned u; } x; x.f = f;
    unsigned r = x.u + 0x7FFFu + ((x.u >> 16) & 1u);
    return (unsigned short)(r >> 16);
}

typedef const __attribute__((address_space(1))) unsigned int* gas_t;
typedef __attribute__((address_space(3))) unsigned int* las_t;
__device__ __forceinline__ void gl_lds16(const void* g, void* l) {
    __builtin_amdgcn_global_load_lds((gas_t)g, (las_t)l, 16, 0, 0);
}

// ---------------- merged: w_iam prep (blocks 0..1151) + fpad border zero (1152..3727)
__global__ __launch_bounds__(256) void k_prep(const float* __restrict__ w_iam,
                                              unsigned short* __restrict__ wp,
                                              unsigned short* __restrict__ fpad) {
    int bid = blockIdx.x;
    if (bid < 1152) {
        int idx = bid * 256 + threadIdx.x;
        int stage = idx >> 12;
        int r = idx & 4095;
        int m = r >> 5, cl = r & 31;
        int tap = stage >> 3, kc = stage & 7;
        int jj = (cl >> 3) ^ ((m >> 1) & 3);
        int c = kc * 32 + jj * 8 + (cl & 7);
        int dy = (tap * 11) >> 5, dx = tap - dy * 3;
        float v = (m < 100) ? w_iam[((m * 256 + c) * 3 + dy) * 3 + dx] : 0.f;
        wp[idx] = f2bf(v);
    } else {
        int idx = (bid - 1152) * 256 + threadIdx.x;
        const int perb = 164864;
        if (idx >= 4 * perb) return;
        int b = idx / perb;
        int r = idx - b * perb;
        int hp, wpp, c;
        if (r < 82944) {
            hp = (r < 41472) ? 0 : 161;
            int r2 = r % 41472;
            wpp = r2 >> 8; c = r2 & 255;
        } else {
            r -= 82944;
            wpp = (r < 40960) ? 0 : 161;
            int r2 = r % 40960;
            hp = 1 + (r2 >> 8); c = r2 & 255;
        }
        fpad[((b * HP_ + hp) * WP_ + wpp) * 256 + c] = 0;
    }
}

// ---------------- features NCHW fp32 -> fpad[b][h+1][w+1][c] bf16 (LDS transpose)
__global__ __launch_bounds__(256) void k_convert(const float* __restrict__ feat,
                                                 unsigned short* __restrict__ fpad) {
    int bid = blockIdx.x;
    int b = bid / 640;
    int h = (bid >> 2) % 160;
    int c0 = (bid & 3) * 64;
    __shared__ float tile[64][161];
    int t = threadIdx.x;
    const float4* src4 = (const float4*)(feat + ((long)(b * 256 + c0) * 160 + h) * 160);
    #pragma unroll
    for (int s = 0; s < 10; ++s) {
        int q = t + s * 256;
        int ci = q / 40;
        int w4 = q - ci * 40;
        float4 v = src4[(long)ci * 6400 + w4];
        tile[ci][w4 * 4 + 0] = v.x;
        tile[ci][w4 * 4 + 1] = v.y;
        tile[ci][w4 * 4 + 2] = v.z;
        tile[ci][w4 * 4 + 3] = v.w;
    }
    __syncthreads();
    int co = (t & 7) * 8, wq = t >> 3;
    unsigned short* dst = fpad + ((long)(b * HP_ + h + 1) * WP_ + 1) * 256 + c0 + co;
    #pragma unroll
    for (int wp = 0; wp < 5; ++wp) {
        int w = wq + wp * 32;
        bf16x8 v;
        #pragma unroll
        for (int j = 0; j < 8; ++j) v[j] = (short)f2bf(tile[co + j][w]);
        *(bf16x8*)(dst + (long)w * 256) = v;
    }
}

// ---------------- conv GEMM (R10 structure, unchanged)
__global__ __launch_bounds__(256, 3) void k_conv(const unsigned short* __restrict__ fpad,
                                                 const unsigned short* __restrict__ wprep,
                                                 const float* __restrict__ b_iam,
                                                 float* __restrict__ iam) {
    int bid = blockIdx.x;
    bid = (bid & 7) * 100 + (bid >> 3);          // XCD swizzle (bijective, 800%8==0)
    int b = bid / 200;
    int p0 = (bid % 200) * 128;
    int tid = threadIdx.x;
    int lane = tid & 63, wid = tid >> 6;
    int wr = wid >> 1, wc = wid & 1;

    __shared__ __align__(16) char smem[24576 + 2 * 8448];   // A @0, B0 @24576, B1 @33024

    int h0 = p0 / 160, w0 = p0 - h0 * 160;
    int istar = 160 - w0;
    const unsigned short* fb = fpad + (long)b * HP_ * WP_ * 256;

    long rterm[2];
    {
        int c = tid & 3;
        #pragma unroll
        for (int i = 0; i < 2; ++i) {
            int r = i * 64 + (tid >> 2);
            rterm[i] = (long)r * 256 + ((c ^ ((r >> 1) & 3)) << 3);
        }
    }
    long rterm2;
    {
        int r = 128 + ((lane & 15) >> 2), c = lane & 3;
        rterm2 = (long)r * 256 + ((c ^ ((r >> 1) & 3)) << 3);
    }

    f32x4 acc[4][4];
    #pragma unroll
    for (int i = 0; i < 4; ++i)
        #pragma unroll
        for (int j = 0; j < 4; ++j)
            #pragma unroll
            for (int k = 0; k < 4; ++k) acc[i][j][k] = 0.f;

    int aBase = (wr << 12) + ((lane & 15) << 6) + ((((lane >> 4) ^ ((lane >> 1) & 3))) << 4);
    int rb[4];
    #pragma unroll
    for (int nf = 0; nf < 4; ++nf) {
        int i = wc * 64 + nf * 16 + (lane & 15);
        rb[nf] = i + 2 * (i >= istar);
    }

    auto issueA = [&](int s) {
        int dy = s >> 3, kc = s & 7;
        #pragma unroll
        for (int dx = 0; dx < 3; ++dx) {
            const unsigned short* ga = wprep + ((long)((dy * 3 + dx) * 8 + kc) << 12) + (tid << 3);
            char* Adst = smem + (dx << 13) + (wid << 10);
            gl_lds16(ga, Adst);
            gl_lds16(ga + 2048, Adst + 4096);
        }
    };
    auto issueB = [&](int s, int bi) {
        int dy = s >> 3, kc = s & 7;
        char* Bd = smem + 24576 + bi * 8448;
        long base = ((long)((h0 + dy) * WP_ + w0)) * 256 + (kc << 5);
        gl_lds16(fb + base + rterm[0], Bd + (wid << 10));
        gl_lds16(fb + base + rterm[1], Bd + 4096 + (wid << 10));
        if (lane < 16) gl_lds16(fb + base + rterm2, Bd + 8192);
    };

    auto compute = [&](int bi) {
        const char* Ab = smem;
        const char* Bb = smem + 24576 + bi * 8448;
        #pragma unroll
        for (int dx = 0; dx < 3; ++dx) {
            bf16x8 af[4], bfv[4];
            #pragma unroll
            for (int mf = 0; mf < 4; ++mf)
                af[mf] = *(const bf16x8*)(Ab + (dx << 13) + aBase + (mf << 10));
            #pragma unroll
            for (int nf = 0; nf < 4; ++nf) {
                int row = rb[nf] + dx;
                bfv[nf] = *(const bf16x8*)(Bb + (row << 6) +
                            ((((lane >> 4) ^ ((row >> 1) & 3))) << 4));
            }
            __builtin_amdgcn_s_setprio(1);
            #pragma unroll
            for (int mf = 0; mf < 4; ++mf)
                #pragma unroll
                for (int nf = 0; nf < 4; ++nf)
                    acc[mf][nf] = __builtin_amdgcn_mfma_f32_16x16x32_bf16(
                        af[mf], bfv[nf], acc[mf][nf], 0, 0, 0);
            __builtin_amdgcn_s_setprio(0);
        }
    };

    issueB(0, 0);
    issueA(0);
    for (int s = 0; s < 24; ++s) {
        if (s < 23) {
            issueB(s + 1, (s + 1) & 1);
            asm volatile("s_waitcnt vmcnt(3)" ::: "memory");
        } else {
            asm volatile("s_waitcnt vmcnt(0)" ::: "memory");
        }
        __builtin_amdgcn_sched_barrier(0);
        __builtin_amdgcn_s_barrier();
        __builtin_amdgcn_sched_barrier(0);
        compute(s & 1);
        __builtin_amdgcn_sched_barrier(0);
        __builtin_amdgcn_s_barrier();
        __builtin_amdgcn_sched_barrier(0);
        if (s < 23) issueA(s + 1);
    }

    float* dst = iam + (long)b * 100 * HW_;
    #pragma unroll
    for (int mf = 0; mf < 4; ++mf)
        #pragma unroll
        for (int nf = 0; nf < 4; ++nf) {
            int p = p0 + wc * 64 + nf * 16 + (lane & 15);
            int m0 = wr * 64 + mf * 16 + ((lane >> 4) << 2);
            #pragma unroll
            for (int j = 0; j < 4; ++j) {
                int m = m0 + j;
                if (m < 100) dst[(long)m * HW_ + p] = acc[mf][nf][j] + b_iam[m];
            }
        }
}

// ---------------- channel-split pooling: 400 blocks, each (b, slice, c-half)
// partials[b*50+sl][112][256] (halves write disjoint 128-col stripes); psum by half 0
__global__ __launch_bounds__(256, 4) void k_pool(const float* __restrict__ feat,
                                                 const float* __restrict__ iam,
                                                 float* __restrict__ partials,
                                                 float* __restrict__ psum) {
    int bid = blockIdx.x;                        // 0..399
    int b = bid / 100;
    int r = bid - b * 100;
    int sl = r >> 1;                             // 0..49
    int ch = r & 1;                              // channel half
    int p0 = sl * 512;
    int c0 = ch * 128;
    int tid = threadIdx.x, lane = tid & 63, wq = tid >> 6;

    __shared__ __align__(16) unsigned short A[128 * 72];    // masks x (64+8)
    __shared__ __align__(16) unsigned short Bl[128 * 72];   // 128 channels x (64+8)
    __shared__ float sums[128];
    if (tid < 128) sums[tid] = 0.f;
    __syncthreads();

    f32x4 acc[7][2];
    #pragma unroll
    for (int i = 0; i < 7; ++i)
        #pragma unroll
        for (int j = 0; j < 2; ++j)
            #pragma unroll
            for (int k = 0; k < 4; ++k) acc[i][j][k] = 0.f;

    int kgrp = (lane >> 4) << 3;

    for (int ks = 0; ks < 8; ++ks) {
        int k0 = p0 + ks * 64;
        // A: exp(iam) bf16, masks padded to 128; half 0 also accumulates row sums
        #pragma unroll
        for (int s = 0; s < 4; ++s) {
            int q = tid + s * 256;
            int mi = q >> 3, j0 = (q & 7) * 8;
            bf16x8 o;
            if (mi < 100) {
                const float4* sp4 = (const float4*)(iam + (long)(b * 100 + mi) * HW_ + k0 + j0);
                float4 v0 = sp4[0], v1 = sp4[1];
                float xv[8] = {v0.x, v0.y, v0.z, v0.w, v1.x, v1.y, v1.z, v1.w};
                float ls = 0.f;
                #pragma unroll
                for (int j = 0; j < 8; ++j) {
                    float e = __expf(xv[j]);
                    o[j] = (short)f2bf(e);
                    ls += e;
                }
                if (ch == 0) atomicAdd(&sums[mi], ls);
            } else {
                #pragma unroll
                for (int j = 0; j < 8; ++j) o[j] = 0;
            }
            *(bf16x8*)(A + mi * 72 + j0) = o;
        }
        // B: this half's 128 channels (fp32 -> bf16)
        #pragma unroll
        for (int s = 0; s < 4; ++s) {
            int q = tid + s * 256;
            int ci = q >> 3, j0 = (q & 7) * 8;
            const float4* sp4 = (const float4*)(feat + (long)(b * 256 + c0 + ci) * HW_ + k0 + j0);
            float4 v0 = sp4[0], v1 = sp4[1];
            float xv[8] = {v0.x, v0.y, v0.z, v0.w, v1.x, v1.y, v1.z, v1.w};
            bf16x8 o;
            #pragma unroll
            for (int j = 0; j < 8; ++j) o[j] = (short)f2bf(xv[j]);
            *(bf16x8*)(Bl + ci * 72 + j0) = o;
        }
        __syncthreads();
        #pragma unroll
        for (int kk = 0; kk < 64; kk += 32) {
            bf16x8 af[7], bfv[2];
            #pragma unroll
            for (int mf = 0; mf < 7; ++mf)
                af[mf] = *(const bf16x8*)(A + (mf * 16 + (lane & 15)) * 72 + kk + kgrp);
            #pragma unroll
            for (int nf = 0; nf < 2; ++nf)
                bfv[nf] = *(const bf16x8*)(Bl + (wq * 32 + nf * 16 + (lane & 15)) * 72 + kk + kgrp);
            #pragma unroll
            for (int mf = 0; mf < 7; ++mf)
                #pragma unroll
                for (int nf = 0; nf < 2; ++nf)
                    acc[mf][nf] = __builtin_amdgcn_mfma_f32_16x16x32_bf16(
                        af[mf], bfv[nf], acc[mf][nf], 0, 0, 0);
        }
        __syncthreads();
    }
    if (ch == 0 && tid < 100) psum[(long)(b * 50 + sl) * 112 + tid] = sums[tid];
    float* dst = partials + (long)(b * 50 + sl) * 112 * 256;
    #pragma unroll
    for (int mf = 0; mf < 7; ++mf)
        #pragma unroll
        for (int nf = 0; nf < 2; ++nf) {
            int m0 = mf * 16 + ((lane >> 4) << 2);
            int c  = c0 + wq * 32 + nf * 16 + (lane & 15);
            #pragma unroll
            for (int j = 0; j < 4; ++j)
                dst[(long)(m0 + j) * 256 + c] = acc[mf][nf][j];
        }
}

// ---------------- fused reduce + fc + heads
__global__ __launch_bounds__(256) void k_redfc(const float* __restrict__ partials,
                                               const float* __restrict__ psum,
                                               const float* __restrict__ w_fc, const float* __restrict__ b_fc,
                                               const float* __restrict__ w_cls, const float* __restrict__ b_cls,
                                               const float* __restrict__ w_ker, const float* __restrict__ b_ker,
                                               const float* __restrict__ w_obj, const float* __restrict__ b_obj,
                                               const float* __restrict__ w_box, const float* __restrict__ b_box,
                                               float* __restrict__ out) {
    int r = blockIdx.x;                         // b*100+m
    int b = r / 100, m = r - b * 100;
    int t = threadIdx.x;
    __shared__ float red[256];
    __shared__ float row[256];
    __shared__ float inst_s[256];

    red[t] = (t < 50) ? psum[(long)(b * 50 + t) * 112 + m] : 0.f;
    __syncthreads();
    for (int o = 128; o > 0; o >>= 1) {
        if (t < o) red[t] += red[t + o];
        __syncthreads();
    }
    float d = red[0];

    float s = 0.f;
    for (int sl = 0; sl < 50; ++sl)
        s += partials[((long)(b * 50 + sl) * 112 + m) * 256 + t];
    row[t] = s / d;
    __syncthreads();
    {
        float acc = b_fc[t];
        const float4* wv = (const float4*)(w_fc + (long)t * 256);
        for (int c = 0; c < 64; ++c) {
            float4 w4 = wv[c];
            acc += w4.x * row[c * 4] + w4.y * row[c * 4 + 1] + w4.z * row[c * 4 + 2] + w4.w * row[c * 4 + 3];
        }
        acc = fmaxf(acc, 0.f);
        inst_s[t] = acc;
        out[10376800 + (long)r * 256 + t] = acc;
    }
    __syncthreads();
    {
        float acc = b_ker[t];
        const float4* wv = (const float4*)(w_ker + (long)t * 256);
        for (int c = 0; c < 64; ++c) {
            float4 w4 = wv[c];
            acc += w4.x * inst_s[c * 4] + w4.y * inst_s[c * 4 + 1] + w4.z * inst_s[c * 4 + 2] + w4.w * inst_s[c * 4 + 3];
        }
        out[32400 + (long)r * 256 + t] = acc;
    }
    if (t < 81) {
        float acc = b_cls[t];
        const float4* wv = (const float4*)(w_cls + (long)t * 256);
        for (int c = 0; c < 64; ++c) {
            float4 w4 = wv[c];
            acc += w4.x * inst_s[c * 4] + w4.y * inst_s[c * 4 + 1] + w4.z * inst_s[c * 4 + 2] + w4.w * inst_s[c * 4 + 3];
        }
        out[(long)r * 81 + t] = acc;
    }
    if (t == 0) {
        float acc = b_obj[0];
        for (int c = 0; c < 256; ++c) acc += w_obj[c] * inst_s[c];
        out[134800 + r] = acc;
    }
    if (t >= 1 && t < 5) {
        int j = t - 1;
        float acc = b_box[j];
        for (int c = 0; c < 256; ++c) acc += w_box[j * 256 + c] * inst_s[c];
        out[135200 + (long)r * 4 + j] = acc;
    }
}

extern "C" void kernel_launch(void* const* d_in, const int* in_sizes, int n_in,
                              void* d_out, int out_size, void* d_ws, size_t ws_size,
                              hipStream_t stream) {
    const float* feat  = (const float*)d_in[0];
    const float* w_iam = (const float*)d_in[1];
    const float* b_iam = (const float*)d_in[2];
    const float* w_fc  = (const float*)d_in[4];
    const float* b_fc  = (const float*)d_in[5];
    const float* w_cls = (const float*)d_in[6];
    const float* b_cls = (const float*)d_in[7];
    const float* w_ker = (const float*)d_in[8];
    const float* b_ker = (const float*)d_in[9];
    const float* w_obj = (const float*)d_in[10];
    const float* b_obj = (const float*)d_in[11];
    const float* w_box = (const float*)d_in[12];
    const float* b_box = (const float*)d_in[13];
    float* out = (float*)d_out;

    char* ws = (char*)d_ws;
    unsigned short* fpad  = (unsigned short*)ws;               //  53,747,712
    unsigned short* wprep = (unsigned short*)(ws + 53747712);  // ->54,337,536
    float* iam = out + 136800;

    // post-conv: partials/psum alias the fpad region (dead after k_conv)
    float* partials = (float*)ws;                              // 22,937,600
    float* psum     = (float*)(ws + 22937600);                 //     89,600

    k_prep   <<<dim3(3728), dim3(256), 0, stream>>>(w_iam, wprep, fpad);
    k_convert<<<dim3(2560), dim3(256), 0, stream>>>(feat, fpad);
    k_conv   <<<dim3(800),  dim3(256), 0, stream>>>(fpad, wprep, b_iam, iam);
    k_pool   <<<dim3(400),  dim3(256), 0, stream>>>(feat, iam, partials, psum);
    k_redfc  <<<dim3(400),  dim3(256), 0, stream>>>(partials, psum, w_fc, b_fc, w_cls, b_cls,
                                                    w_ker, b_ker, w_obj, b_obj, w_box, b_box, out);
}

// Round 12
// 191.597 us; speedup vs baseline: 1.0659x; 1.0659x over previous
//
#include <hip/hip_runtime.h>
#include <hip/hip_bf16.h>

typedef __attribute__((ext_vector_type(8))) short bf16x8;
typedef __attribute__((ext_vector_type(4))) float f32x4;

#define HW_ 25600
#define HP_ 162
#define WP_ 162

__device__ __forceinline__ unsigned short f2bf(float f) {
    union { float f; unsigned u; } x; x.f = f;
    unsigned r = x.u + 0x7FFFu + ((x.u >> 16) & 1u);
    return (unsigned short)(r >> 16);
}
__device__ __forceinline__ float bf2f(unsigned short v) {
    union { unsigned u; float f; } x; x.u = ((unsigned)v) << 16;
    return x.f;
}

typedef const __attribute__((address_space(1))) unsigned int* gas_t;
typedef __attribute__((address_space(3))) unsigned int* las_t;
__device__ __forceinline__ void gl_lds16(const void* g, void* l) {
    __builtin_amdgcn_global_load_lds((gas_t)g, (las_t)l, 16, 0, 0);
}

// ---------------- merged: w_iam prep (blocks 0..1151) + fpad border zero (1152..3727)
__global__ __launch_bounds__(256) void k_prep(const float* __restrict__ w_iam,
                                              unsigned short* __restrict__ wp,
                                              unsigned short* __restrict__ fpad) {
    int bid = blockIdx.x;
    if (bid < 1152) {
        int idx = bid * 256 + threadIdx.x;
        int stage = idx >> 12;
        int r = idx & 4095;
        int m = r >> 5, cl = r & 31;
        int tap = stage >> 3, kc = stage & 7;
        int jj = (cl >> 3) ^ ((m >> 1) & 3);
        int c = kc * 32 + jj * 8 + (cl & 7);
        int dy = (tap * 11) >> 5, dx = tap - dy * 3;
        float v = (m < 100) ? w_iam[((m * 256 + c) * 3 + dy) * 3 + dx] : 0.f;
        wp[idx] = f2bf(v);
    } else {
        int idx = (bid - 1152) * 256 + threadIdx.x;
        const int perb = 164864;
        if (idx >= 4 * perb) return;
        int b = idx / perb;
        int r = idx - b * perb;
        int hp, wpp, c;
        if (r < 82944) {
            hp = (r < 41472) ? 0 : 161;
            int r2 = r % 41472;
            wpp = r2 >> 8; c = r2 & 255;
        } else {
            r -= 82944;
            wpp = (r < 40960) ? 0 : 161;
            int r2 = r % 40960;
            hp = 1 + (r2 >> 8); c = r2 & 255;
        }
        fpad[((b * HP_ + hp) * WP_ + wpp) * 256 + c] = 0;
    }
}

// ---------------- features NCHW fp32 -> fpad[b][h+1][w+1][c] bf16 (LDS transpose)
__global__ __launch_bounds__(256) void k_convert(const float* __restrict__ feat,
                                                 unsigned short* __restrict__ fpad) {
    int bid = blockIdx.x;
    int b = bid / 640;
    int h = (bid >> 2) % 160;
    int c0 = (bid & 3) * 64;
    __shared__ float tile[64][161];
    int t = threadIdx.x;
    const float4* src4 = (const float4*)(feat + ((long)(b * 256 + c0) * 160 + h) * 160);
    #pragma unroll
    for (int s = 0; s < 10; ++s) {
        int q = t + s * 256;
        int ci = q / 40;
        int w4 = q - ci * 40;
        float4 v = src4[(long)ci * 6400 + w4];
        tile[ci][w4 * 4 + 0] = v.x;
        tile[ci][w4 * 4 + 1] = v.y;
        tile[ci][w4 * 4 + 2] = v.z;
        tile[ci][w4 * 4 + 3] = v.w;
    }
    __syncthreads();
    int co = (t & 7) * 8, wq = t >> 3;
    unsigned short* dst = fpad + ((long)(b * HP_ + h + 1) * WP_ + 1) * 256 + c0 + co;
    #pragma unroll
    for (int wp = 0; wp < 5; ++wp) {
        int w = wq + wp * 32;
        bf16x8 v;
        #pragma unroll
        for (int j = 0; j < 8; ++j) v[j] = (short)f2bf(tile[co + j][w]);
        *(bf16x8*)(dst + (long)w * 256) = v;
    }
}

// ---------------- conv GEMM (R10 structure, unchanged — 83 us proven)
__global__ __launch_bounds__(256, 3) void k_conv(const unsigned short* __restrict__ fpad,
                                                 const unsigned short* __restrict__ wprep,
                                                 const float* __restrict__ b_iam,
                                                 float* __restrict__ iam) {
    int bid = blockIdx.x;
    bid = (bid & 7) * 100 + (bid >> 3);          // XCD swizzle (bijective, 800%8==0)
    int b = bid / 200;
    int p0 = (bid % 200) * 128;
    int tid = threadIdx.x;
    int lane = tid & 63, wid = tid >> 6;
    int wr = wid >> 1, wc = wid & 1;

    __shared__ __align__(16) char smem[24576 + 2 * 8448];   // A @0, B0 @24576, B1 @33024

    int h0 = p0 / 160, w0 = p0 - h0 * 160;
    int istar = 160 - w0;
    const unsigned short* fb = fpad + (long)b * HP_ * WP_ * 256;

    long rterm[2];
    {
        int c = tid & 3;
        #pragma unroll
        for (int i = 0; i < 2; ++i) {
            int r = i * 64 + (tid >> 2);
            rterm[i] = (long)r * 256 + ((c ^ ((r >> 1) & 3)) << 3);
        }
    }
    long rterm2;
    {
        int r = 128 + ((lane & 15) >> 2), c = lane & 3;
        rterm2 = (long)r * 256 + ((c ^ ((r >> 1) & 3)) << 3);
    }

    f32x4 acc[4][4];
    #pragma unroll
    for (int i = 0; i < 4; ++i)
        #pragma unroll
        for (int j = 0; j < 4; ++j)
            #pragma unroll
            for (int k = 0; k < 4; ++k) acc[i][j][k] = 0.f;

    int aBase = (wr << 12) + ((lane & 15) << 6) + ((((lane >> 4) ^ ((lane >> 1) & 3))) << 4);
    int rb[4];
    #pragma unroll
    for (int nf = 0; nf < 4; ++nf) {
        int i = wc * 64 + nf * 16 + (lane & 15);
        rb[nf] = i + 2 * (i >= istar);
    }

    auto issueA = [&](int s) {
        int dy = s >> 3, kc = s & 7;
        #pragma unroll
        for (int dx = 0; dx < 3; ++dx) {
            const unsigned short* ga = wprep + ((long)((dy * 3 + dx) * 8 + kc) << 12) + (tid << 3);
            char* Adst = smem + (dx << 13) + (wid << 10);
            gl_lds16(ga, Adst);
            gl_lds16(ga + 2048, Adst + 4096);
        }
    };
    auto issueB = [&](int s, int bi) {
        int dy = s >> 3, kc = s & 7;
        char* Bd = smem + 24576 + bi * 8448;
        long base = ((long)((h0 + dy) * WP_ + w0)) * 256 + (kc << 5);
        gl_lds16(fb + base + rterm[0], Bd + (wid << 10));
        gl_lds16(fb + base + rterm[1], Bd + 4096 + (wid << 10));
        if (lane < 16) gl_lds16(fb + base + rterm2, Bd + 8192);
    };

    auto compute = [&](int bi) {
        const char* Ab = smem;
        const char* Bb = smem + 24576 + bi * 8448;
        #pragma unroll
        for (int dx = 0; dx < 3; ++dx) {
            bf16x8 af[4], bfv[4];
            #pragma unroll
            for (int mf = 0; mf < 4; ++mf)
                af[mf] = *(const bf16x8*)(Ab + (dx << 13) + aBase + (mf << 10));
            #pragma unroll
            for (int nf = 0; nf < 4; ++nf) {
                int row = rb[nf] + dx;
                bfv[nf] = *(const bf16x8*)(Bb + (row << 6) +
                            ((((lane >> 4) ^ ((row >> 1) & 3))) << 4));
            }
            __builtin_amdgcn_s_setprio(1);
            #pragma unroll
            for (int mf = 0; mf < 4; ++mf)
                #pragma unroll
                for (int nf = 0; nf < 4; ++nf)
                    acc[mf][nf] = __builtin_amdgcn_mfma_f32_16x16x32_bf16(
                        af[mf], bfv[nf], acc[mf][nf], 0, 0, 0);
            __builtin_amdgcn_s_setprio(0);
        }
    };

    issueB(0, 0);
    issueA(0);
    for (int s = 0; s < 24; ++s) {
        if (s < 23) {
            issueB(s + 1, (s + 1) & 1);
            asm volatile("s_waitcnt vmcnt(3)" ::: "memory");
        } else {
            asm volatile("s_waitcnt vmcnt(0)" ::: "memory");
        }
        __builtin_amdgcn_sched_barrier(0);
        __builtin_amdgcn_s_barrier();
        __builtin_amdgcn_sched_barrier(0);
        compute(s & 1);
        __builtin_amdgcn_sched_barrier(0);
        __builtin_amdgcn_s_barrier();
        __builtin_amdgcn_sched_barrier(0);
        if (s < 23) issueA(s + 1);
    }

    float* dst = iam + (long)b * 100 * HW_;
    #pragma unroll
    for (int mf = 0; mf < 4; ++mf)
        #pragma unroll
        for (int nf = 0; nf < 4; ++nf) {
            int p = p0 + wc * 64 + nf * 16 + (lane & 15);
            int m0 = wr * 64 + mf * 16 + ((lane >> 4) << 2);
            #pragma unroll
            for (int j = 0; j < 4; ++j) {
                int m = m0 + j;
                if (m < 100) dst[(long)m * HW_ + p] = acc[mf][nf][j] + b_iam[m];
            }
        }
}

// ---------------- pixel-split pooling: 400 blocks = 4b x 100 slices of 256 px.
// No duplicated work vs R6 (slices partition pixels); partials in bf16 so
// total partials bytes stay 22.9 MB despite 2x slices.
__global__ __launch_bounds__(256, 2) void k_pool(const float* __restrict__ feat,
                                                 const float* __restrict__ iam,
                                                 unsigned short* __restrict__ partials,
                                                 float* __restrict__ psum) {
    int bid = blockIdx.x;                        // b*100 + sl
    int b = bid / 100;
    int sl = bid - b * 100;
    int p0 = sl * 256;
    int tid = threadIdx.x, lane = tid & 63, wq = tid >> 6;

    __shared__ __align__(16) unsigned short A[128 * 72];
    __shared__ __align__(16) unsigned short Bl[256 * 72];
    __shared__ float sums[128];
    if (tid < 128) sums[tid] = 0.f;
    __syncthreads();

    f32x4 acc[7][4];
    #pragma unroll
    for (int i = 0; i < 7; ++i)
        #pragma unroll
        for (int j = 0; j < 4; ++j)
            #pragma unroll
            for (int k = 0; k < 4; ++k) acc[i][j][k] = 0.f;

    int kgrp = (lane >> 4) << 3;

    for (int ks = 0; ks < 4; ++ks) {
        int k0 = p0 + ks * 64;
        for (int s = 0; s < 4; ++s) {
            int q = tid + s * 256;
            int mi = q >> 3, j0 = (q & 7) * 8;
            bf16x8 o;
            if (mi < 100) {
                const float4* sp4 = (const float4*)(iam + (long)(b * 100 + mi) * HW_ + k0 + j0);
                float4 v0 = sp4[0], v1 = sp4[1];
                float xv[8] = {v0.x, v0.y, v0.z, v0.w, v1.x, v1.y, v1.z, v1.w};
                float ls = 0.f;
                #pragma unroll
                for (int j = 0; j < 8; ++j) {
                    float e = __expf(xv[j]);
                    o[j] = (short)f2bf(e);
                    ls += e;
                }
                atomicAdd(&sums[mi], ls);
            } else {
                #pragma unroll
                for (int j = 0; j < 8; ++j) o[j] = 0;
            }
            *(bf16x8*)(A + mi * 72 + j0) = o;
        }
        for (int s = 0; s < 8; ++s) {
            int q = tid + s * 256;
            int ci = q >> 3, j0 = (q & 7) * 8;
            const float4* sp4 = (const float4*)(feat + (long)(b * 256 + ci) * HW_ + k0 + j0);
            float4 v0 = sp4[0], v1 = sp4[1];
            float xv[8] = {v0.x, v0.y, v0.z, v0.w, v1.x, v1.y, v1.z, v1.w};
            bf16x8 o;
            #pragma unroll
            for (int j = 0; j < 8; ++j) o[j] = (short)f2bf(xv[j]);
            *(bf16x8*)(Bl + ci * 72 + j0) = o;
        }
        __syncthreads();
        #pragma unroll
        for (int kk = 0; kk < 64; kk += 32) {
            bf16x8 af[7], bfv[4];
            #pragma unroll
            for (int mf = 0; mf < 7; ++mf)
                af[mf] = *(const bf16x8*)(A + (mf * 16 + (lane & 15)) * 72 + kk + kgrp);
            #pragma unroll
            for (int nf = 0; nf < 4; ++nf)
                bfv[nf] = *(const bf16x8*)(Bl + (wq * 64 + nf * 16 + (lane & 15)) * 72 + kk + kgrp);
            #pragma unroll
            for (int mf = 0; mf < 7; ++mf)
                #pragma unroll
                for (int nf = 0; nf < 4; ++nf)
                    acc[mf][nf] = __builtin_amdgcn_mfma_f32_16x16x32_bf16(
                        af[mf], bfv[nf], acc[mf][nf], 0, 0, 0);
        }
        __syncthreads();
    }
    if (tid < 100) psum[(long)bid * 112 + tid] = sums[tid];
    unsigned short* dst = partials + (long)bid * 112 * 256;
    #pragma unroll
    for (int mf = 0; mf < 7; ++mf)
        #pragma unroll
        for (int nf = 0; nf < 4; ++nf) {
            int m0 = mf * 16 + ((lane >> 4) << 2);
            int c  = wq * 64 + nf * 16 + (lane & 15);
            #pragma unroll
            for (int j = 0; j < 4; ++j)
                dst[(long)(m0 + j) * 256 + c] = f2bf(acc[mf][nf][j]);
        }
}

// ---------------- fused reduce (bf16 partials, 100 slices) + fc + heads
__global__ __launch_bounds__(256) void k_redfc(const unsigned short* __restrict__ partials,
                                               const float* __restrict__ psum,
                                               const float* __restrict__ w_fc, const float* __restrict__ b_fc,
                                               const float* __restrict__ w_cls, const float* __restrict__ b_cls,
                                               const float* __restrict__ w_ker, const float* __restrict__ b_ker,
                                               const float* __restrict__ w_obj, const float* __restrict__ b_obj,
                                               const float* __restrict__ w_box, const float* __restrict__ b_box,
                                               float* __restrict__ out) {
    int r = blockIdx.x;                         // b*100+m
    int b = r / 100, m = r - b * 100;
    int t = threadIdx.x;
    __shared__ float red[256];
    __shared__ float row[256];
    __shared__ float inst_s[256];

    red[t] = (t < 100) ? psum[(long)(b * 100 + t) * 112 + m] : 0.f;
    __syncthreads();
    for (int o = 128; o > 0; o >>= 1) {
        if (t < o) red[t] += red[t + o];
        __syncthreads();
    }
    float d = red[0];

    float s = 0.f;
    for (int sl = 0; sl < 100; ++sl)
        s += bf2f(partials[((long)(b * 100 + sl) * 112 + m) * 256 + t]);
    row[t] = s / d;
    __syncthreads();
    {
        float acc = b_fc[t];
        const float4* wv = (const float4*)(w_fc + (long)t * 256);
        for (int c = 0; c < 64; ++c) {
            float4 w4 = wv[c];
            acc += w4.x * row[c * 4] + w4.y * row[c * 4 + 1] + w4.z * row[c * 4 + 2] + w4.w * row[c * 4 + 3];
        }
        acc = fmaxf(acc, 0.f);
        inst_s[t] = acc;
        out[10376800 + (long)r * 256 + t] = acc;
    }
    __syncthreads();
    {
        float acc = b_ker[t];
        const float4* wv = (const float4*)(w_ker + (long)t * 256);
        for (int c = 0; c < 64; ++c) {
            float4 w4 = wv[c];
            acc += w4.x * inst_s[c * 4] + w4.y * inst_s[c * 4 + 1] + w4.z * inst_s[c * 4 + 2] + w4.w * inst_s[c * 4 + 3];
        }
        out[32400 + (long)r * 256 + t] = acc;
    }
    if (t < 81) {
        float acc = b_cls[t];
        const float4* wv = (const float4*)(w_cls + (long)t * 256);
        for (int c = 0; c < 64; ++c) {
            float4 w4 = wv[c];
            acc += w4.x * inst_s[c * 4] + w4.y * inst_s[c * 4 + 1] + w4.z * inst_s[c * 4 + 2] + w4.w * inst_s[c * 4 + 3];
        }
        out[(long)r * 81 + t] = acc;
    }
    if (t == 0) {
        float acc = b_obj[0];
        for (int c = 0; c < 256; ++c) acc += w_obj[c] * inst_s[c];
        out[134800 + r] = acc;
    }
    if (t >= 1 && t < 5) {
        int j = t - 1;
        float acc = b_box[j];
        for (int c = 0; c < 256; ++c) acc += w_box[j * 256 + c] * inst_s[c];
        out[135200 + (long)r * 4 + j] = acc;
    }
}

extern "C" void kernel_launch(void* const* d_in, const int* in_sizes, int n_in,
                              void* d_out, int out_size, void* d_ws, size_t ws_size,
                              hipStream_t stream) {
    const float* feat  = (const float*)d_in[0];
    const float* w_iam = (const float*)d_in[1];
    const float* b_iam = (const float*)d_in[2];
    const float* w_fc  = (const float*)d_in[4];
    const float* b_fc  = (const float*)d_in[5];
    const float* w_cls = (const float*)d_in[6];
    const float* b_cls = (const float*)d_in[7];
    const float* w_ker = (const float*)d_in[8];
    const float* b_ker = (const float*)d_in[9];
    const float* w_obj = (const float*)d_in[10];
    const float* b_obj = (const float*)d_in[11];
    const float* w_box = (const float*)d_in[12];
    const float* b_box = (const float*)d_in[13];
    float* out = (float*)d_out;

    char* ws = (char*)d_ws;
    unsigned short* fpad  = (unsigned short*)ws;               //  53,747,712
    unsigned short* wprep = (unsigned short*)(ws + 53747712);  // ->54,337,536
    float* iam = out + 136800;

    // post-conv: partials/psum alias the fpad region (dead after k_conv)
    unsigned short* partials = (unsigned short*)ws;            // 22,937,600 B (bf16, 400 slices)
    float* psum              = (float*)(ws + 22937600);        //    179,200 B

    k_prep   <<<dim3(3728), dim3(256), 0, stream>>>(w_iam, wprep, fpad);
    k_convert<<<dim3(2560), dim3(256), 0, stream>>>(feat, fpad);
    k_conv   <<<dim3(800),  dim3(256), 0, stream>>>(fpad, wprep, b_iam, iam);
    k_pool   <<<dim3(400),  dim3(256), 0, stream>>>(feat, iam, partials, psum);
    k_redfc  <<<dim3(400),  dim3(256), 0, stream>>>(partials, psum, w_fc, b_fc, w_cls, b_cls,
                                                    w_ker, b_ker, w_obj, b_obj, w_box, b_box, out);
}

// Round 13
// 173.175 us; speedup vs baseline: 1.1792x; 1.1064x over previous
//
#include <hip/hip_runtime.h>
#include <hip/hip_bf16.h>

typedef __attribute__((ext_vector_type(8))) short bf16x8;
typedef __attribute__((ext_vector_type(4))) float f32x4;

#define HW_ 25600
#define HP_ 162
#define WP_ 162

__device__ __forceinline__ unsigned short f2bf(float f) {
    union { float f; unsigned u; } x; x.f = f;
    unsigned r = x.u + 0x7FFFu + ((x.u >> 16) & 1u);
    return (unsigned short)(r >> 16);
}
__device__ __forceinline__ float bf2f(unsigned short v) {
    union { unsigned u; float f; } x; x.u = ((unsigned)v) << 16;
    return x.f;
}

typedef const __attribute__((address_space(1))) unsigned int* gas_t;
typedef __attribute__((address_space(3))) unsigned int* las_t;
__device__ __forceinline__ void gl_lds16(const void* g, void* l) {
    __builtin_amdgcn_global_load_lds((gas_t)g, (las_t)l, 16, 0, 0);
}

// ---------------- merged: w_iam prep (0..1151) + border zero (1152..3727) + convert (3728..6287)
__global__ __launch_bounds__(256) void k_prepcvt(const float* __restrict__ w_iam,
                                                 unsigned short* __restrict__ wp,
                                                 const float* __restrict__ feat,
                                                 unsigned short* __restrict__ fpad) {
    int bid = blockIdx.x;
    if (bid < 1152) {
        int idx = bid * 256 + threadIdx.x;
        int stage = idx >> 12;
        int r = idx & 4095;
        int m = r >> 5, cl = r & 31;
        int tap = stage >> 3, kc = stage & 7;
        int jj = (cl >> 3) ^ ((m >> 1) & 3);
        int c = kc * 32 + jj * 8 + (cl & 7);
        int dy = (tap * 11) >> 5, dx = tap - dy * 3;
        float v = (m < 100) ? w_iam[((m * 256 + c) * 3 + dy) * 3 + dx] : 0.f;
        wp[idx] = f2bf(v);
    } else if (bid < 3728) {
        int idx = (bid - 1152) * 256 + threadIdx.x;
        const int perb = 164864;
        if (idx >= 4 * perb) return;
        int b = idx / perb;
        int r = idx - b * perb;
        int hp, wpp, c;
        if (r < 82944) {
            hp = (r < 41472) ? 0 : 161;
            int r2 = r % 41472;
            wpp = r2 >> 8; c = r2 & 255;
        } else {
            r -= 82944;
            wpp = (r < 40960) ? 0 : 161;
            int r2 = r % 40960;
            hp = 1 + (r2 >> 8); c = r2 & 255;
        }
        fpad[((b * HP_ + hp) * WP_ + wpp) * 256 + c] = 0;
    } else {
        int cb = bid - 3728;
        int b = cb / 640;
        int h = (cb >> 2) % 160;
        int c0 = (cb & 3) * 64;
        __shared__ float tile[64][161];
        int t = threadIdx.x;
        const float4* src4 = (const float4*)(feat + ((long)(b * 256 + c0) * 160 + h) * 160);
        #pragma unroll
        for (int s = 0; s < 10; ++s) {
            int q = t + s * 256;
            int ci = q / 40;
            int w4 = q - ci * 40;
            float4 v = src4[(long)ci * 6400 + w4];
            tile[ci][w4 * 4 + 0] = v.x;
            tile[ci][w4 * 4 + 1] = v.y;
            tile[ci][w4 * 4 + 2] = v.z;
            tile[ci][w4 * 4 + 3] = v.w;
        }
        __syncthreads();
        int co = (t & 7) * 8, wq = t >> 3;
        unsigned short* dst = fpad + ((long)(b * HP_ + h + 1) * WP_ + 1) * 256 + c0 + co;
        #pragma unroll
        for (int wp2 = 0; wp2 < 5; ++wp2) {
            int w = wq + wp2 * 32;
            bf16x8 v;
            #pragma unroll
            for (int j = 0; j < 8; ++j) v[j] = (short)f2bf(tile[co + j][w]);
            *(bf16x8*)(dst + (long)w * 256) = v;
        }
    }
}

// ---------------- conv GEMM: 512 threads, 256-px tiles, 400 blocks.
// 8 waves = 2m x 4p of 64x64. A (3dx x 128m x 32k) single-buffered @0;
// B (272 rows x 32k) double-buffered @24576/@41984. Counted vmcnt.
__global__ __launch_bounds__(512, 4) void k_conv(const unsigned short* __restrict__ fpad,
                                                 const unsigned short* __restrict__ wprep,
                                                 const float* __restrict__ b_iam,
                                                 float* __restrict__ iam) {
    int bid = blockIdx.x;
    bid = (bid & 7) * 50 + (bid >> 3);           // XCD swizzle (400 % 8 == 0, bijective)
    int b = bid / 100;
    int p0 = (bid % 100) * 256;
    int tid = threadIdx.x;
    int lane = tid & 63, wid = tid >> 6;
    int wr = wid >> 2, wc = wid & 3;             // 2m x 4p wave grid

    __shared__ __align__(16) char smem[24576 + 2 * 17408];   // 59392 B

    int h0 = p0 / 160, w0 = p0 - h0 * 160;
    int istar1 = 160 - w0, istar2 = 320 - w0;
    const unsigned short* fb = fpad + (long)b * HP_ * WP_ * 256;

    // B staging element offsets (src chunk-permuted so linear LDS is swizzled, rule #21)
    long rt0, rt1, rt2;
    {
        int c = tid & 3;
        int r0 = tid >> 2;                       // issue0: rows 0..127
        rt0 = (long)r0 * 256 + ((c ^ ((r0 >> 1) & 3)) << 3);
        int r1 = 128 + (tid >> 2);               // issue1: rows 128..255
        rt1 = (long)r1 * 256 + ((c ^ ((r1 >> 1) & 3)) << 3);
        int r2 = 256 + (lane >> 2);              // issue2 (wave 0 only): rows 256..271
        int c2 = lane & 3;
        rt2 = (long)r2 * 256 + ((c2 ^ ((r2 >> 1) & 3)) << 3);
    }

    f32x4 acc[4][4];
    #pragma unroll
    for (int i = 0; i < 4; ++i)
        #pragma unroll
        for (int j = 0; j < 4; ++j)
            #pragma unroll
            for (int k = 0; k < 4; ++k) acc[i][j][k] = 0.f;

    int aBase = (wr << 12) + ((lane & 15) << 6) + ((((lane >> 4) ^ ((lane >> 1) & 3))) << 4);
    int rb[4];
    #pragma unroll
    for (int nf = 0; nf < 4; ++nf) {
        int i = wc * 64 + nf * 16 + (lane & 15);  // 0..255
        rb[nf] = i + 2 * (i >= istar1) + 2 * (i >= istar2);
    }

    auto issueA = [&](int s) {                   // 3 loads/thread
        int dy = s >> 3, kc = s & 7;
        #pragma unroll
        for (int dx = 0; dx < 3; ++dx) {
            const unsigned short* ga = wprep + ((long)((dy * 3 + dx) * 8 + kc) << 12) + (tid << 3);
            gl_lds16(ga, smem + (dx << 13) + (wid << 10));
        }
    };
    auto issueB = [&](int s, int bi) {           // wave0: 3 loads, waves 1-7: 2
        int dy = s >> 3, kc = s & 7;
        char* Bd = smem + 24576 + bi * 17408;
        long base = ((long)((h0 + dy) * WP_ + w0)) * 256 + (kc << 5);
        gl_lds16(fb + base + rt0, Bd + (wid << 10));
        gl_lds16(fb + base + rt1, Bd + 8192 + (wid << 10));
        if (wid == 0) gl_lds16(fb + base + rt2, Bd + 16384);
    };

    auto compute = [&](int bi) {
        const char* Ab = smem;
        const char* Bb = smem + 24576 + bi * 17408;
        #pragma unroll
        for (int dx = 0; dx < 3; ++dx) {
            bf16x8 af[4], bfv[4];
            #pragma unroll
            for (int mf = 0; mf < 4; ++mf)
                af[mf] = *(const bf16x8*)(Ab + (dx << 13) + aBase + (mf << 10));
            #pragma unroll
            for (int nf = 0; nf < 4; ++nf) {
                int row = rb[nf] + dx;
                bfv[nf] = *(const bf16x8*)(Bb + (row << 6) +
                            ((((lane >> 4) ^ ((row >> 1) & 3))) << 4));
            }
            __builtin_amdgcn_s_setprio(1);
            #pragma unroll
            for (int mf = 0; mf < 4; ++mf)
                #pragma unroll
                for (int nf = 0; nf < 4; ++nf)
                    acc[mf][nf] = __builtin_amdgcn_mfma_f32_16x16x32_bf16(
                        af[mf], bfv[nf], acc[mf][nf], 0, 0, 0);
            __builtin_amdgcn_s_setprio(0);
        }
    };

    issueB(0, 0);
    issueA(0);
    for (int s = 0; s < 24; ++s) {
        if (s < 23) {
            issueB(s + 1, (s + 1) & 1);
            // outstanding: A(s) 3 + B(s) (2|3) + B(s+1) (2|3); leave only B(s+1)
            if (wid == 0) asm volatile("s_waitcnt vmcnt(3)" ::: "memory");
            else          asm volatile("s_waitcnt vmcnt(2)" ::: "memory");
        } else {
            asm volatile("s_waitcnt vmcnt(0)" ::: "memory");
        }
        __builtin_amdgcn_sched_barrier(0);
        __builtin_amdgcn_s_barrier();            // all waves' A(s),B(s) landed
        __builtin_amdgcn_sched_barrier(0);
        compute(s & 1);
        __builtin_amdgcn_sched_barrier(0);
        __builtin_amdgcn_s_barrier();            // all waves done reading A-buf
        __builtin_amdgcn_sched_barrier(0);
        if (s < 23) issueA(s + 1);               // safe to overwrite A now
    }

    float* dst = iam + (long)b * 100 * HW_;
    #pragma unroll
    for (int mf = 0; mf < 4; ++mf)
        #pragma unroll
        for (int nf = 0; nf < 4; ++nf) {
            int p = p0 + wc * 64 + nf * 16 + (lane & 15);
            int m0 = wr * 64 + mf * 16 + ((lane >> 4) << 2);
            #pragma unroll
            for (int j = 0; j < 4; ++j) {
                int m = m0 + j;
                if (m < 100) dst[(long)m * HW_ + p] = acc[mf][nf][j] + b_iam[m];
            }
        }
}

// ---------------- pixel-split pooling (R12-proven): 400 blocks, bf16 partials
__global__ __launch_bounds__(256, 2) void k_pool(const float* __restrict__ feat,
                                                 const float* __restrict__ iam,
                                                 unsigned short* __restrict__ partials,
                                                 float* __restrict__ psum) {
    int bid = blockIdx.x;                        // b*100 + sl
    int b = bid / 100;
    int sl = bid - b * 100;
    int p0 = sl * 256;
    int tid = threadIdx.x, lane = tid & 63, wq = tid >> 6;

    __shared__ __align__(16) unsigned short A[128 * 72];
    __shared__ __align__(16) unsigned short Bl[256 * 72];
    __shared__ float sums[128];
    if (tid < 128) sums[tid] = 0.f;
    __syncthreads();

    f32x4 acc[7][4];
    #pragma unroll
    for (int i = 0; i < 7; ++i)
        #pragma unroll
        for (int j = 0; j < 4; ++j)
            #pragma unroll
            for (int k = 0; k < 4; ++k) acc[i][j][k] = 0.f;

    int kgrp = (lane >> 4) << 3;

    for (int ks = 0; ks < 4; ++ks) {
        int k0 = p0 + ks * 64;
        for (int s = 0; s < 4; ++s) {
            int q = tid + s * 256;
            int mi = q >> 3, j0 = (q & 7) * 8;
            bf16x8 o;
            if (mi < 100) {
                const float4* sp4 = (const float4*)(iam + (long)(b * 100 + mi) * HW_ + k0 + j0);
                float4 v0 = sp4[0], v1 = sp4[1];
                float xv[8] = {v0.x, v0.y, v0.z, v0.w, v1.x, v1.y, v1.z, v1.w};
                float ls = 0.f;
                #pragma unroll
                for (int j = 0; j < 8; ++j) {
                    float e = __expf(xv[j]);
                    o[j] = (short)f2bf(e);
                    ls += e;
                }
                atomicAdd(&sums[mi], ls);
            } else {
                #pragma unroll
                for (int j = 0; j < 8; ++j) o[j] = 0;
            }
            *(bf16x8*)(A + mi * 72 + j0) = o;
        }
        for (int s = 0; s < 8; ++s) {
            int q = tid + s * 256;
            int ci = q >> 3, j0 = (q & 7) * 8;
            const float4* sp4 = (const float4*)(feat + (long)(b * 256 + ci) * HW_ + k0 + j0);
            float4 v0 = sp4[0], v1 = sp4[1];
            float xv[8] = {v0.x, v0.y, v0.z, v0.w, v1.x, v1.y, v1.z, v1.w};
            bf16x8 o;
            #pragma unroll
            for (int j = 0; j < 8; ++j) o[j] = (short)f2bf(xv[j]);
            *(bf16x8*)(Bl + ci * 72 + j0) = o;
        }
        __syncthreads();
        #pragma unroll
        for (int kk = 0; kk < 64; kk += 32) {
            bf16x8 af[7], bfv[4];
            #pragma unroll
            for (int mf = 0; mf < 7; ++mf)
                af[mf] = *(const bf16x8*)(A + (mf * 16 + (lane & 15)) * 72 + kk + kgrp);
            #pragma unroll
            for (int nf = 0; nf < 4; ++nf)
                bfv[nf] = *(const bf16x8*)(Bl + (wq * 64 + nf * 16 + (lane & 15)) * 72 + kk + kgrp);
            #pragma unroll
            for (int mf = 0; mf < 7; ++mf)
                #pragma unroll
                for (int nf = 0; nf < 4; ++nf)
                    acc[mf][nf] = __builtin_amdgcn_mfma_f32_16x16x32_bf16(
                        af[mf], bfv[nf], acc[mf][nf], 0, 0, 0);
        }
        __syncthreads();
    }
    if (tid < 100) psum[(long)bid * 112 + tid] = sums[tid];
    unsigned short* dst = partials + (long)bid * 112 * 256;
    #pragma unroll
    for (int mf = 0; mf < 7; ++mf)
        #pragma unroll
        for (int nf = 0; nf < 4; ++nf) {
            int m0 = mf * 16 + ((lane >> 4) << 2);
            int c  = wq * 64 + nf * 16 + (lane & 15);
            #pragma unroll
            for (int j = 0; j < 4; ++j)
                dst[(long)(m0 + j) * 256 + c] = f2bf(acc[mf][nf][j]);
        }
}

// ---------------- fused reduce (bf16 partials, 100 slices) + fc + heads
__global__ __launch_bounds__(256) void k_redfc(const unsigned short* __restrict__ partials,
                                               const float* __restrict__ psum,
                                               const float* __restrict__ w_fc, const float* __restrict__ b_fc,
                                               const float* __restrict__ w_cls, const float* __restrict__ b_cls,
                                               const float* __restrict__ w_ker, const float* __restrict__ b_ker,
                                               const float* __restrict__ w_obj, const float* __restrict__ b_obj,
                                               const float* __restrict__ w_box, const float* __restrict__ b_box,
                                               float* __restrict__ out) {
    int r = blockIdx.x;                         // b*100+m
    int b = r / 100, m = r - b * 100;
    int t = threadIdx.x;
    __shared__ float red[256];
    __shared__ float row[256];
    __shared__ float inst_s[256];

    red[t] = (t < 100) ? psum[(long)(b * 100 + t) * 112 + m] : 0.f;
    __syncthreads();
    for (int o = 128; o > 0; o >>= 1) {
        if (t < o) red[t] += red[t + o];
        __syncthreads();
    }
    float d = red[0];

    float s = 0.f;
    for (int sl = 0; sl < 100; ++sl)
        s += bf2f(partials[((long)(b * 100 + sl) * 112 + m) * 256 + t]);
    row[t] = s / d;
    __syncthreads();
    {
        float acc = b_fc[t];
        const float4* wv = (const float4*)(w_fc + (long)t * 256);
        for (int c = 0; c < 64; ++c) {
            float4 w4 = wv[c];
            acc += w4.x * row[c * 4] + w4.y * row[c * 4 + 1] + w4.z * row[c * 4 + 2] + w4.w * row[c * 4 + 3];
        }
        acc = fmaxf(acc, 0.f);
        inst_s[t] = acc;
        out[10376800 + (long)r * 256 + t] = acc;
    }
    __syncthreads();
    {
        float acc = b_ker[t];
        const float4* wv = (const float4*)(w_ker + (long)t * 256);
        for (int c = 0; c < 64; ++c) {
            float4 w4 = wv[c];
            acc += w4.x * inst_s[c * 4] + w4.y * inst_s[c * 4 + 1] + w4.z * inst_s[c * 4 + 2] + w4.w * inst_s[c * 4 + 3];
        }
        out[32400 + (long)r * 256 + t] = acc;
    }
    if (t < 81) {
        float acc = b_cls[t];
        const float4* wv = (const float4*)(w_cls + (long)t * 256);
        for (int c = 0; c < 64; ++c) {
            float4 w4 = wv[c];
            acc += w4.x * inst_s[c * 4] + w4.y * inst_s[c * 4 + 1] + w4.z * inst_s[c * 4 + 2] + w4.w * inst_s[c * 4 + 3];
        }
        out[(long)r * 81 + t] = acc;
    }
    if (t == 0) {
        float acc = b_obj[0];
        for (int c = 0; c < 256; ++c) acc += w_obj[c] * inst_s[c];
        out[134800 + r] = acc;
    }
    if (t >= 1 && t < 5) {
        int j = t - 1;
        float acc = b_box[j];
        for (int c = 0; c < 256; ++c) acc += w_box[j * 256 + c] * inst_s[c];
        out[135200 + (long)r * 4 + j] = acc;
    }
}

extern "C" void kernel_launch(void* const* d_in, const int* in_sizes, int n_in,
                              void* d_out, int out_size, void* d_ws, size_t ws_size,
                              hipStream_t stream) {
    const float* feat  = (const float*)d_in[0];
    const float* w_iam = (const float*)d_in[1];
    const float* b_iam = (const float*)d_in[2];
    const float* w_fc  = (const float*)d_in[4];
    const float* b_fc  = (const float*)d_in[5];
    const float* w_cls = (const float*)d_in[6];
    const float* b_cls = (const float*)d_in[7];
    const float* w_ker = (const float*)d_in[8];
    const float* b_ker = (const float*)d_in[9];
    const float* w_obj = (const float*)d_in[10];
    const float* b_obj = (const float*)d_in[11];
    const float* w_box = (const float*)d_in[12];
    const float* b_box = (const float*)d_in[13];
    float* out = (float*)d_out;

    char* ws = (char*)d_ws;
    unsigned short* fpad  = (unsigned short*)ws;               //  53,747,712
    unsigned short* wprep = (unsigned short*)(ws + 53747712);  // ->54,337,536
    float* iam = out + 136800;

    // post-conv: partials/psum alias the fpad region (dead after k_conv)
    unsigned short* partials = (unsigned short*)ws;            // 22,937,600 B (bf16, 400 slices)
    float* psum              = (float*)(ws + 22937600);        //    179,200 B

    k_prepcvt<<<dim3(6288), dim3(256), 0, stream>>>(w_iam, wprep, feat, fpad);
    k_conv   <<<dim3(400),  dim3(512), 0, stream>>>(fpad, wprep, b_iam, iam);
    k_pool   <<<dim3(400),  dim3(256), 0, stream>>>(feat, iam, partials, psum);
    k_redfc  <<<dim3(400),  dim3(256), 0, stream>>>(partials, psum, w_fc, b_fc, w_cls, b_cls,
                                                    w_ker, b_ker, w_obj, b_obj, w_box, b_box, out);
}